// Round 3
// baseline (175.978 us; speedup 1.0000x reference)
//
#include <hip/hip_runtime.h>
#include <math.h>

// ---- problem constants -----------------------------------------------------
#define NPTS    2048
#define NBINS   2049            // k = 0..2048
#define NFRAMES 2049            // f = 0..2048
#define U       192             // truncated Gaussian support, u_c in [-96,95] (4.8 sigma)
#define PAD     96
#define XPLEN   2560            // padded bf16 signal per batch (zeros outside)

// ---- GEMM tiling -----------------------------------------------------------
#define MTOT    4224            // interleaved re/im rows 2*2049=4098, pad to 33*128
#define MBLK    33
#define NBLK    9               // frames padded to 9*256 = 2304
#define BM      128
#define BN      256
#define SPAN    (BN + U)        // 448
#define SSTRIDE 464             // span copy stride (els): 232 dwords == 8 mod 32
#define NCOPY   8               // shift-copies -> 16B-aligned single b128 B reads

typedef __attribute__((ext_vector_type(8))) short short8_t;   // bf16x8 (4 VGPR)
typedef __attribute__((ext_vector_type(4))) float float4_t;   // fp32x4 acc

static __device__ __forceinline__ unsigned short f2bf(float f) {
    unsigned u = __float_as_uint(f);
    unsigned r = (u + 0x7fffu + ((u >> 16) & 1u)) >> 16;      // RNE
    return (unsigned short)r;
}

// ---- fused prep: blocks 0..7 mean+pad signal; blocks 8.. generate W --------
// W rows m = 2k+p (p=0 re / 1 im); each wgen thread fills one 32-u chunk.
#define WCH 6                   // 192/32 chunks per row
#define WGBLK ((MTOT * WCH + 255) / 256)   // 99 blocks
__global__ void prep_kernel(const float* __restrict__ x, const float* __restrict__ lambd,
                            unsigned short* __restrict__ xp, unsigned short* __restrict__ W) {
    if (blockIdx.x < 8) {
        // ---- per-batch mean + padded bf16 signal ----
        __shared__ float red[256];
        const int b = blockIdx.x;
        float s = 0.f;
        for (int t = threadIdx.x; t < NPTS; t += 256) s += x[b * NPTS + t];
        red[threadIdx.x] = s;
        __syncthreads();
        for (int off = 128; off > 0; off >>= 1) {
            if (threadIdx.x < off) red[threadIdx.x] += red[threadIdx.x + off];
            __syncthreads();
        }
        const float mean = red[0] * (1.f / (float)NPTS);
        for (int t = threadIdx.x; t < XPLEN; t += 256) {
            const int s2 = t - PAD;
            float v = (s2 >= 0 && s2 < NPTS) ? (x[b * NPTS + s2] - mean) : 0.f;
            xp[b * XPLEN + t] = f2bf(v);
        }
        return;
    }
    // ---- W[m][u] via rotation + Gaussian recurrences ----
    const int idx = (blockIdx.x - 8) * 256 + threadIdx.x;
    if (idx >= MTOT * WCH) return;
    const int m  = idx / WCH;
    const int ch = idx - m * WCH;
    const int k = m >> 1, p = m & 1;
    unsigned int* wp = (unsigned int*)(W + (size_t)m * U + ch * 32);  // 64B aligned
    if (k >= NBINS) {
        #pragma unroll
        for (int j = 0; j < 16; ++j) wp[j] = 0u;
        return;
    }
    const float sigma  = fabsf(lambd[0]);
    const float inv2s2 = 0.5f / (sigma * sigma);
    const int   u0i = ch * 32 - PAD;
    const float u0  = (float)u0i;
    // theta(u) = pi*k*u/2048 = 2*pi * ((k*u) mod 4096)/4096 -- exact int reduction,
    // keeps __sincosf args small (fast path, no Payne-Hanek).
    const float TWO_PI = 6.28318530717958647692f;
    float sn, cs, sd, cd;
    __sincosf(TWO_PI * (1.f / 4096.f) * (float)((k * u0i) & 4095), &sn, &cs);
    __sincosf(TWO_PI * (1.f / 4096.f) * (float)k, &sd, &cd);
    float       g  = __expf(-u0 * u0 * inv2s2);
    float       gr = __expf(-(2.f * u0 + 1.f) * inv2s2);
    const float gq = __expf(-2.f * inv2s2);
    #pragma unroll
    for (int j = 0; j < 16; ++j) {
        unsigned short lo = f2bf(g * (p ? sn : cs));
        float cn = cs * cd - sn * sd; sn = fmaf(sn, cd, cs * sd); cs = cn;
        g *= gr; gr *= gq;
        unsigned short hi = f2bf(g * (p ? sn : cs));
        cn = cs * cd - sn * sd; sn = fmaf(sn, cd, cs * sd); cs = cn;
        g *= gr; gr *= gq;
        wp[j] = (unsigned int)lo | ((unsigned int)hi << 16);
    }
}

// ---- main: banded MFMA GEMM + power epilogue -------------------------------
// P[k,f] = (sum_u Wr[k,u] X[u,f])^2 + (sum_u Wi[k,u] X[u,f])^2, X[u,f]=xp[u+f]
// - B (Hankel): 8-slot register ring from LDS shift-copies (18 b128/lane total)
// - A (W rows): direct global->VGPR, 1-step prefetch (W is L2-resident; no Alds,
//   no staging barriers -- the kernel has exactly ONE __syncthreads)
__global__ __launch_bounds__(256, 2) void spec_mfma(
        const unsigned short* __restrict__ W, const unsigned short* __restrict__ xp,
        float* __restrict__ out) {
    __shared__ unsigned short span[NCOPY * SSTRIDE];   // 7424 B: 8 shift-copies

    const int tid = threadIdx.x;
    const int b  = blockIdx.z;
    const int n0 = blockIdx.x * BN;                 // frame origin
    const int m0 = blockIdx.y * BM;                 // interleaved-row origin

    // span shift-copies: copy c holds xp[n0 + t + c], t in [0, SPAN); b32 writes
    {
        const unsigned short* xpb = xp + b * XPLEN;
        for (int i = tid; i < NCOPY * (SPAN / 2); i += 256) {
            const int c  = i / (SPAN / 2);
            const int t2 = (i - c * (SPAN / 2)) * 2;
            const unsigned lo = xpb[n0 + t2 + c];
            const unsigned hi = xpb[n0 + t2 + c + 1];
            *(unsigned*)(span + c * SSTRIDE + t2) = lo | (hi << 16);
        }
    }

    const int lane = tid & 63;
    const int wv   = tid >> 6;
    const int wm   = (wv & 1) * 64;                 // wave M-quadrant
    const int wn   = (wv >> 1) * 128;               // wave N-half
    const int col  = lane & 15;
    const int q    = lane >> 4;

    // A direct-global base: fragment (mt, j) = abase + mt*16*U + j*32 (16B aligned)
    const unsigned short* abase = W + (size_t)(m0 + wm + col) * U + q * 8;

    // B Hankel base: copy cc = col&7 makes (col-cc)+8q a multiple of 8 -> 16B aligned
    const int cc = col & 7;
    const unsigned short* bbase = span + cc * SSTRIDE + (wn + col - cc) + 8 * q;

    float4_t acc[4][8];
    #pragma unroll
    for (int mt = 0; mt < 4; ++mt)
        #pragma unroll
        for (int nt = 0; nt < 8; ++nt)
            acc[mt][nt] = (float4_t){0.f, 0.f, 0.f, 0.f};

    // A prefetch for step 0 (global; overlaps span staging)
    short8_t afc[4], afn[4];
    #pragma unroll
    for (int mt = 0; mt < 4; ++mt)
        afc[mt] = *(const short8_t*)(abase + mt * 16 * U);

    __syncthreads();   // span ready (the only barrier)

    // B ring init: slots d = 0..7 hold fragment offset 16*d (= step j=0 needs)
    short8_t bf[8];
    #pragma unroll
    for (int d = 0; d < 8; ++d)
        bf[d] = *(const short8_t*)(bbase + 16 * d);

    #pragma unroll
    for (int j = 0; j < 6; ++j) {                   // K-steps of 32
        // prefetch A for step j+1 (global, L2-hot) and B ring for step j+1 (LDS)
        short8_t nb0, nb1;
        if (j < 5) {
            #pragma unroll
            for (int mt = 0; mt < 4; ++mt)
                afn[mt] = *(const short8_t*)(abase + mt * 16 * U + (j + 1) * 32);
            nb0 = *(const short8_t*)(bbase + 16 * (2 * j + 8));
            nb1 = *(const short8_t*)(bbase + 16 * (2 * j + 9));
        }
        #pragma unroll
        for (int mt = 0; mt < 4; ++mt)
            #pragma unroll
            for (int nt = 0; nt < 8; ++nt)
                acc[mt][nt] = __builtin_amdgcn_mfma_f32_16x16x32_bf16(
                    afc[mt], bf[(nt + 2 * j) & 7], acc[mt][nt], 0, 0, 0);
        if (j < 5) {
            bf[(2 * j) & 7]     = nb0;
            bf[(2 * j + 1) & 7] = nb1;
            #pragma unroll
            for (int mt = 0; mt < 4; ++mt)
                afc[mt] = afn[mt];
        }
    }

    // epilogue: acc rows (q*4 + r): r=0,1 -> (re,im) of k; r=2,3 -> k+1
    const int fbase = n0 + wn + col;
    #pragma unroll
    for (int mt = 0; mt < 4; ++mt) {
        const int mrow = m0 + wm + mt * 16 + q * 4;   // even
        const int kk0  = mrow >> 1;
        #pragma unroll
        for (int nt = 0; nt < 8; ++nt) {
            const int f = fbase + nt * 16;
            if (f < NFRAMES) {
                const float4_t a = acc[mt][nt];
                const float p0 = a[0] * a[0] + a[1] * a[1];
                const float p1 = a[2] * a[2] + a[3] * a[3];
                if (kk0 < NBINS)
                    out[((size_t)b * NBINS + kk0) * NFRAMES + f] = p0;
                if (kk0 + 1 < NBINS)
                    out[((size_t)b * NBINS + kk0 + 1) * NFRAMES + f] = p1;
            }
        }
    }
}

// ---- launch ---------------------------------------------------------------
extern "C" void kernel_launch(void* const* d_in, const int* in_sizes, int n_in,
                              void* d_out, int out_size, void* d_ws, size_t ws_size,
                              hipStream_t stream) {
    const float* x     = (const float*)d_in[0];
    const float* lambd = (const float*)d_in[1];
    float*       out   = (float*)d_out;

    // ws layout: [0, 40960) xp bf16 (8*2560) | [43264, +1622016) W bf16
    char* ws = (char*)d_ws;
    unsigned short* xp = (unsigned short*)ws;
    unsigned short* W  = (unsigned short*)(ws + 43264);

    hipLaunchKernelGGL(prep_kernel, dim3(8 + WGBLK), dim3(256), 0, stream, x, lambd, xp, W);

    dim3 grid(NBLK, MBLK, 8);   // (frame-tiles, row-tiles, batch)
    hipLaunchKernelGGL(spec_mfma, grid, dim3(256), 0, stream, W, xp, out);
}

// Round 4
// 168.657 us; speedup vs baseline: 1.0434x; 1.0434x over previous
//
#include <hip/hip_runtime.h>
#include <math.h>

// ---- problem constants -----------------------------------------------------
#define NPTS    2048
#define NBINS   2049            // k = 0..2048
#define NFRAMES 2049            // f = 0..2048
#define U       192             // truncated Gaussian support, u_c in [-96,95] (4.8 sigma)
#define PAD     96
#define XPLEN   2560            // padded bf16 signal per batch (zeros outside)

// ---- GEMM tiling -----------------------------------------------------------
#define MTOT    4224            // interleaved re/im rows 2*2049=4098, pad to 33*128
#define MBLK    33
#define NBLK    9               // frames padded to 9*256 = 2304
#define BM      128
#define BN      256
#define BK      64
#define SPAN    (BN + U)        // 448
#define SSTRIDE 464             // span copy stride (els): 232 dwords == 8 mod 32
#define NCOPY   8               // shift-copies -> 16B-aligned single b128 B reads
#define ASTRIDE 72              // A_lds row stride (els): 16B-aligned, bank-staggered
#define ABUF    (BM * ASTRIDE)  // els per A buffer

typedef __attribute__((ext_vector_type(8))) short short8_t;   // bf16x8 (4 VGPR)
typedef __attribute__((ext_vector_type(4))) float float4_t;   // fp32x4 acc

static __device__ __forceinline__ unsigned short f2bf(float f) {
    unsigned u = __float_as_uint(f);
    unsigned r = (u + 0x7fffu + ((u >> 16) & 1u)) >> 16;      // RNE
    return (unsigned short)r;
}

// ---- fused prep: blocks 0..7 mean+pad signal; blocks 8.. generate W --------
// W rows m = 2k+p (p=0 re / 1 im); each wgen thread fills one 32-u chunk.
#define WCH 6                   // 192/32 chunks per row
#define WGBLK ((MTOT * WCH + 255) / 256)   // 99 blocks
__global__ void prep_kernel(const float* __restrict__ x, const float* __restrict__ lambd,
                            unsigned short* __restrict__ xp, unsigned short* __restrict__ W) {
    if (blockIdx.x < 8) {
        // ---- per-batch mean + padded bf16 signal ----
        __shared__ float red[256];
        const int b = blockIdx.x;
        float s = 0.f;
        for (int t = threadIdx.x; t < NPTS; t += 256) s += x[b * NPTS + t];
        red[threadIdx.x] = s;
        __syncthreads();
        for (int off = 128; off > 0; off >>= 1) {
            if (threadIdx.x < off) red[threadIdx.x] += red[threadIdx.x + off];
            __syncthreads();
        }
        const float mean = red[0] * (1.f / (float)NPTS);
        for (int t = threadIdx.x; t < XPLEN; t += 256) {
            const int s2 = t - PAD;
            float v = (s2 >= 0 && s2 < NPTS) ? (x[b * NPTS + s2] - mean) : 0.f;
            xp[b * XPLEN + t] = f2bf(v);
        }
        return;
    }
    // ---- W[m][u] via rotation + Gaussian recurrences ----
    const int idx = (blockIdx.x - 8) * 256 + threadIdx.x;
    if (idx >= MTOT * WCH) return;
    const int m  = idx / WCH;
    const int ch = idx - m * WCH;
    const int k = m >> 1, p = m & 1;
    unsigned int* wp = (unsigned int*)(W + (size_t)m * U + ch * 32);  // 64B aligned
    if (k >= NBINS) {
        #pragma unroll
        for (int j = 0; j < 16; ++j) wp[j] = 0u;
        return;
    }
    const float sigma  = fabsf(lambd[0]);
    const float inv2s2 = 0.5f / (sigma * sigma);
    const int   u0i = ch * 32 - PAD;
    const float u0  = (float)u0i;
    // theta(u) = pi*k*u/2048 = 2*pi * ((k*u) mod 4096)/4096 -- exact int reduction,
    // keeps __sincosf args small (fast path, no Payne-Hanek).
    const float TWO_PI = 6.28318530717958647692f;
    float sn, cs, sd, cd;
    __sincosf(TWO_PI * (1.f / 4096.f) * (float)((k * u0i) & 4095), &sn, &cs);
    __sincosf(TWO_PI * (1.f / 4096.f) * (float)k, &sd, &cd);
    float       g  = __expf(-u0 * u0 * inv2s2);
    float       gr = __expf(-(2.f * u0 + 1.f) * inv2s2);
    const float gq = __expf(-2.f * inv2s2);
    #pragma unroll
    for (int j = 0; j < 16; ++j) {
        unsigned short lo = f2bf(g * (p ? sn : cs));
        float cn = cs * cd - sn * sd; sn = fmaf(sn, cd, cs * sd); cs = cn;
        g *= gr; gr *= gq;
        unsigned short hi = f2bf(g * (p ? sn : cs));
        cn = cs * cd - sn * sd; sn = fmaf(sn, cd, cs * sd); cs = cn;
        g *= gr; gr *= gq;
        wp[j] = (unsigned int)lo | ((unsigned int)hi << 16);
    }
}

// ---- main: banded MFMA GEMM + power epilogue -------------------------------
// P[k,f] = (sum_u Wr[k,u] X[u,f])^2 + (sum_u Wi[k,u] X[u,f])^2, X[u,f]=xp[u+f]
// Best-measured structure (R2): A via LDS double-buffer; B (Hankel) via
// 8-slot register ring from LDS shift-copies (18 b128/lane total vs 48).
__global__ __launch_bounds__(256, 2) void spec_mfma(
        const unsigned short* __restrict__ W, const unsigned short* __restrict__ xp,
        float* __restrict__ out) {
    __shared__ unsigned short Alds[2 * ABUF];          // 36864 B double buffer
    __shared__ unsigned short span[NCOPY * SSTRIDE];   // 7424 B: 8 shift-copies

    const int tid = threadIdx.x;
    const int b  = blockIdx.z;
    const int n0 = blockIdx.x * BN;                 // frame origin
    const int m0 = blockIdx.y * BM;                 // interleaved-row origin

    // span shift-copies: copy c holds xp[n0 + t + c], t in [0, SPAN); b32 writes
    {
        const unsigned short* xpb = xp + b * XPLEN;
        for (int i = tid; i < NCOPY * (SPAN / 2); i += 256) {
            const int c  = i / (SPAN / 2);
            const int t2 = (i - c * (SPAN / 2)) * 2;
            const unsigned lo = xpb[n0 + t2 + c];
            const unsigned hi = xpb[n0 + t2 + c + 1];
            *(unsigned*)(span + c * SSTRIDE + t2) = lo | (hi << 16);
        }
    }

    const int lane = tid & 63;
    const int wv   = tid >> 6;
    const int wm   = (wv & 1) * 64;                 // wave M-quadrant
    const int wn   = (wv >> 1) * 128;               // wave N-half
    const int col  = lane & 15;
    const int q    = lane >> 4;

    // A staging map: 2 threads per row, 32 els (64 B) each
    const int row  = tid >> 1;
    const int half = tid & 1;
    const unsigned short* wrow = W + (size_t)(m0 + row) * U + half * 32;
    const int lbase = row * ASTRIDE + half * 32;

    // B Hankel base: copy cc = col&7 makes (col-cc)+8q a multiple of 8 -> 16B aligned
    const int cc = col & 7;
    const unsigned short* bbase = span + cc * SSTRIDE + (wn + col - cc) + 8 * q;

    float4_t acc[4][8];
    #pragma unroll
    for (int mt = 0; mt < 4; ++mt)
        #pragma unroll
        for (int nt = 0; nt < 8; ++nt)
            acc[mt][nt] = (float4_t){0.f, 0.f, 0.f, 0.f};

    // prologue: stage 0 -> buf0, prefetch stage 1 into regs
    float4 r0, r1, r2, r3;
    {
        const float4* g4 = (const float4*)(wrow);
        r0 = g4[0]; r1 = g4[1]; r2 = g4[2]; r3 = g4[3];
        float4* l4 = (float4*)(Alds + lbase);
        l4[0] = r0; l4[1] = r1; l4[2] = r2; l4[3] = r3;
        const float4* g5 = (const float4*)(wrow + BK);
        r0 = g5[0]; r1 = g5[1]; r2 = g5[2]; r3 = g5[3];
    }
    __syncthreads();

    // B ring init: slots d = 0..7 hold fragment offset 16*d (= step j=0 needs)
    short8_t bf[8];
    #pragma unroll
    for (int d = 0; d < 8; ++d)
        bf[d] = *(const short8_t*)(bbase + 16 * d);

    #pragma unroll
    for (int s = 0; s < 3; ++s) {
        if (s < 2) {   // write prefetched tile s+1 into the other buffer
            float4* l4 = (float4*)(Alds + ((s + 1) & 1) * ABUF + lbase);
            l4[0] = r0; l4[1] = r1; l4[2] = r2; l4[3] = r3;
        }
        if (s < 1) {   // prefetch tile s+2
            const float4* g4 = (const float4*)(wrow + (s + 2) * BK);
            r0 = g4[0]; r1 = g4[1]; r2 = g4[2]; r3 = g4[3];
        }
        const unsigned short* cur = Alds + (s & 1) * ABUF;
        #pragma unroll
        for (int ks = 0; ks < 2; ++ks) {
            const int j  = s * 2 + ks;              // K-step 0..5
            const int kk = ks * 32;
            short8_t af[4];
            #pragma unroll
            for (int mt = 0; mt < 4; ++mt)
                af[mt] = *(const short8_t*)(cur + (wm + mt * 16 + col) * ASTRIDE + kk + q * 8);
            // ring prefetch for step j+1: offsets 16*(2j+8), 16*(2j+9)
            // (SSA under full unroll -> no WAR with this step's MFMAs)
            short8_t nb0, nb1;
            if (j < 5) {
                nb0 = *(const short8_t*)(bbase + 16 * (2 * j + 8));
                nb1 = *(const short8_t*)(bbase + 16 * (2 * j + 9));
            }
            #pragma unroll
            for (int mt = 0; mt < 4; ++mt)
                #pragma unroll
                for (int nt = 0; nt < 8; ++nt)
                    acc[mt][nt] = __builtin_amdgcn_mfma_f32_16x16x32_bf16(
                        af[mt], bf[(nt + 2 * j) & 7], acc[mt][nt], 0, 0, 0);
            if (j < 5) {
                bf[(2 * j) & 7]     = nb0;
                bf[(2 * j + 1) & 7] = nb1;
            }
        }
        __syncthreads();
    }

    // epilogue: acc rows (q*4 + r): r=0,1 -> (re,im) of k; r=2,3 -> k+1
    const int fbase = n0 + wn + col;
    #pragma unroll
    for (int mt = 0; mt < 4; ++mt) {
        const int mrow = m0 + wm + mt * 16 + q * 4;   // even
        const int kk0  = mrow >> 1;
        #pragma unroll
        for (int nt = 0; nt < 8; ++nt) {
            const int f = fbase + nt * 16;
            if (f < NFRAMES) {
                const float4_t a = acc[mt][nt];
                const float p0 = a[0] * a[0] + a[1] * a[1];
                const float p1 = a[2] * a[2] + a[3] * a[3];
                if (kk0 < NBINS)
                    out[((size_t)b * NBINS + kk0) * NFRAMES + f] = p0;
                if (kk0 + 1 < NBINS)
                    out[((size_t)b * NBINS + kk0 + 1) * NFRAMES + f] = p1;
            }
        }
    }
}

// ---- launch ---------------------------------------------------------------
extern "C" void kernel_launch(void* const* d_in, const int* in_sizes, int n_in,
                              void* d_out, int out_size, void* d_ws, size_t ws_size,
                              hipStream_t stream) {
    const float* x     = (const float*)d_in[0];
    const float* lambd = (const float*)d_in[1];
    float*       out   = (float*)d_out;

    // ws layout: [0, 40960) xp bf16 (8*2560) | [43264, +1622016) W bf16
    char* ws = (char*)d_ws;
    unsigned short* xp = (unsigned short*)ws;
    unsigned short* W  = (unsigned short*)(ws + 43264);

    hipLaunchKernelGGL(prep_kernel, dim3(8 + WGBLK), dim3(256), 0, stream, x, lambd, xp, W);

    dim3 grid(NBLK, MBLK, 8);   // (frame-tiles, row-tiles, batch)
    hipLaunchKernelGGL(spec_mfma, grid, dim3(256), 0, stream, W, xp, out);
}